// Round 6
// baseline (95.093 us; speedup 1.0000x reference)
//
#include <hip/hip_runtime.h>
#include <math.h>

#define B_  32
#define C_  256
#define H_  64
#define W_  64
#define HW  (H_*W_)          // 4096
#define HW4 (HW/4)           // 1024
#define RPB 4                // channel rows per block (grid 2048 = 8 blocks/CU)

typedef float f32x4 __attribute__((ext_vector_type(4)));

__device__ __forceinline__ float clamp01(float v) {
    return fminf(fmaxf(v, 0.0f), 1.0f);
}

// ---------------------------------------------------------------------------
// K1: fused mask+pf. Per block (b, 4 channels):
//   header: box math -> 64-entry rm pattern table (bit-identical FMA chain)
//           -> rm row in LDS + area (all cheap)
//   stream: pf[b,c] = dot(feat row, rm)/area for 4 rows
//   g==0 block also writes out_rm and boxes.
// ---------------------------------------------------------------------------
__global__ __launch_bounds__(256) void kern_pf(
    const float* __restrict__ feat, const float* __restrict__ xywh,
    const float* __restrict__ conv1_w, const float* __restrict__ conv1_b,
    const float* __restrict__ conv2_w, const float* __restrict__ conv2_b,
    float* __restrict__ out_boxes, float* __restrict__ out_rm,
    float* __restrict__ out_pf)
{
    const int blk = blockIdx.x;          // b*64 + g
    const int b = blk >> 6;
    const int g = blk & 63;
    const int c0 = g * RPB;
    const int t = threadIdx.x;

    __shared__ float sw1[16 * 9];
    __shared__ float sb1[16];
    __shared__ float sw2[16];
    __shared__ float tbl[64];
    __shared__ int   xpat[64];
    __shared__ int   ypat[64];
    __shared__ f32x4 rm4_lds[HW4];       // 16 KB, 16B aligned
    __shared__ float sreda[4];
    __shared__ f32x4 sredv[4];

    float* rm_lds = (float*)rm4_lds;

    if (t < 144)                 sw1[t]       = conv1_w[t];
    else if (t < 160)            sb1[t - 144] = conv1_b[t - 144];
    else if (t < 176)            sw2[t - 160] = conv2_w[t - 160];
    const float b2v = conv2_b[0];

    // box math (replicated; scalar broadcast loads)
    const float xc = xywh[b * 4 + 0];
    const float yc = xywh[b * 4 + 1];
    const float bw = xywh[b * 4 + 2];
    const float bh = xywh[b * 4 + 3];

    float x1 = clamp01(xc - bw * 0.5f);
    float y1 = clamp01(yc - bh * 0.5f);
    float x2 = clamp01(xc + bw * 0.5f);
    float y2 = clamp01(yc + bh * 0.5f);
    float xl = fminf(x1, x2), xh = fmaxf(x1, x2);
    float yl = fminf(y1, y2), yh = fmaxf(y1, y2);
    float w_ = fmaxf(xh - xl, 1e-6f);
    float h_ = fmaxf(yh - yl, 1e-6f);
    float cx = (xh + xl) * 0.5f, cy = (yh + yl) * 0.5f;
    float bx1 = clamp01(cx - w_ * 0.5f);
    float by1 = clamp01(cy - h_ * 0.5f);
    float bx2 = clamp01(cx + w_ * 0.5f);
    float by2 = clamp01(cy + h_ * 0.5f);

    if (t == 0 && g == 0) {
        out_boxes[b * 4 + 0] = bx1;
        out_boxes[b * 4 + 1] = by1;
        out_boxes[b * 4 + 2] = bx2;
        out_boxes[b * 4 + 3] = by2;
    }

    float ww = fmaxf(bx2 - bx1, 1e-4f);
    float hh = fmaxf(by2 - by1, 1e-4f);
    float diag = sqrtf(ww * ww + hh * hh);
    float margin = fminf(fmaxf(diag * 0.2f, 0.02f), 0.2f);
    float mx1 = clamp01(bx1 - margin);
    float my1 = clamp01(by1 - margin);
    float mx2 = clamp01(bx2 + margin);
    float my2 = clamp01(by2 + margin);

    __syncthreads();   // weights visible

    // pattern tables + 64-entry rm table
    if (t < 64) {
        const int x = t;
        int p = 0;
        #pragma unroll
        for (int k = 0; k < 3; ++k) {
            const int xx = x + k - 1;
            float gx = (float)((double)xx / 63.0);
            bool in = (xx >= 0) && (xx < W_) && (gx >= mx1) && (gx <= mx2);
            p |= (in ? 1 : 0) << k;
        }
        xpat[x] = p;
    } else if (t < 128) {
        const int y = t - 64;
        int p = 0;
        #pragma unroll
        for (int k = 0; k < 3; ++k) {
            const int yy = y + k - 1;
            float gy = (float)((double)yy / 63.0);
            bool in = (yy >= 0) && (yy < H_) && (gy >= my1) && (gy <= my2);
            p |= (in ? 1 : 0) << k;
        }
        ypat[y] = p;
    } else if (t < 192) {
        const int e = t - 128;           // e = yp*8 + xp
        const int xp = e & 7, yp = e >> 3;
        float mv[9];
        #pragma unroll
        for (int ky = 0; ky < 3; ++ky)
            #pragma unroll
            for (int kx = 0; kx < 3; ++kx)
                mv[ky * 3 + kx] = (((yp >> ky) & 1) && ((xp >> kx) & 1)) ? 1.0f : 0.0f;
        float z = b2v;
        #pragma unroll
        for (int oc = 0; oc < 16; ++oc) {
            float hsum = sb1[oc];
            #pragma unroll
            for (int k = 0; k < 9; ++k) hsum = fmaf(mv[k], sw1[oc * 9 + k], hsum);
            z = fmaf(fmaxf(hsum, 0.0f), sw2[oc], z);
        }
        tbl[e] = 1.0f / (1.0f + expf(-z));
    }
    __syncthreads();

    // fill rm row in LDS + area partial (identical order in every block)
    float asum = 0.0f;
    for (int p = t; p < HW; p += 256) {
        const int y = p >> 6;
        const int x = p & 63;
        float rm = tbl[ypat[y] * 8 + xpat[x]];
        rm_lds[p] = rm;
        asum += rm;
    }
    #pragma unroll
    for (int off = 32; off > 0; off >>= 1) asum += __shfl_down(asum, off, 64);
    const int lane = t & 63, wid = t >> 6;
    if (lane == 0) sreda[wid] = asum;
    __syncthreads();
    const float inv = 1.0f / fmaxf(sreda[0] + sreda[1] + sreda[2] + sreda[3], 1.0f);

    // designated block persists rm for K3
    if (g == 0) {
        f32x4* orm = (f32x4*)(out_rm + (size_t)b * HW);
        for (int i = t; i < HW4; i += 256) orm[i] = rm4_lds[i];
    }

    // stream: dot 4 feat rows with rm (rm from LDS)
    const f32x4* fr = (const f32x4*)(feat + ((size_t)b * C_ + c0) * HW);
    float s0 = 0.f, s1 = 0.f, s2 = 0.f, s3 = 0.f;
    #pragma unroll 2
    for (int i = t; i < HW4; i += 256) {
        f32x4 r = rm4_lds[i];
        f32x4 f0 = fr[i];
        f32x4 f1 = fr[i + HW4];
        f32x4 f2 = fr[i + 2 * HW4];
        f32x4 f3 = fr[i + 3 * HW4];
        s0 = fmaf(f0.x, r.x, fmaf(f0.y, r.y, fmaf(f0.z, r.z, fmaf(f0.w, r.w, s0))));
        s1 = fmaf(f1.x, r.x, fmaf(f1.y, r.y, fmaf(f1.z, r.z, fmaf(f1.w, r.w, s1))));
        s2 = fmaf(f2.x, r.x, fmaf(f2.y, r.y, fmaf(f2.z, r.z, fmaf(f2.w, r.w, s2))));
        s3 = fmaf(f3.x, r.x, fmaf(f3.y, r.y, fmaf(f3.z, r.z, fmaf(f3.w, r.w, s3))));
    }

    #pragma unroll
    for (int off = 32; off > 0; off >>= 1) {
        s0 += __shfl_down(s0, off, 64);
        s1 += __shfl_down(s1, off, 64);
        s2 += __shfl_down(s2, off, 64);
        s3 += __shfl_down(s3, off, 64);
    }
    if (lane == 0) { f32x4 v; v.x = s0; v.y = s1; v.z = s2; v.w = s3; sredv[wid] = v; }
    __syncthreads();
    if (t == 0) {
        f32x4 t0 = sredv[0], t1 = sredv[1], t2 = sredv[2], t3 = sredv[3];
        out_pf[b * C_ + c0 + 0] = (t0.x + t1.x + t2.x + t3.x) * inv;
        out_pf[b * C_ + c0 + 1] = (t0.y + t1.y + t2.y + t3.y) * inv;
        out_pf[b * C_ + c0 + 2] = (t0.z + t1.z + t2.z + t3.z) * inv;
        out_pf[b * C_ + c0 + 3] = (t0.w + t1.w + t2.w + t3.w) * inv;
    }
}

// ---------------------------------------------------------------------------
// K2: fused 2-layer MLP. 2 blocks per batch: which=0 -> pre-biased ch gate,
// which=1 -> guided_lang.
// ---------------------------------------------------------------------------
__global__ __launch_bounds__(256) void kern_mlp(
    const float* __restrict__ pf, const float* __restrict__ lang,
    const float* __restrict__ cg_w1, const float* __restrict__ cg_b1,
    const float* __restrict__ cg_w2, const float* __restrict__ cg_b2,
    const float* __restrict__ lf_w1, const float* __restrict__ lf_b1,
    const float* __restrict__ lf_w2, const float* __restrict__ lf_b2,
    float* __restrict__ ws_cg, float* __restrict__ out_gl)
{
    const int b = blockIdx.x >> 1;
    const int which = blockIdx.x & 1;
    const int t = threadIdx.x;
    __shared__ float fus[512];
    __shared__ float hid[256];

    fus[t]       = pf[b * 256 + t];
    fus[256 + t] = lang[b * 256 + t];

    const float* w1 = which ? lf_w1 : cg_w1;
    const float* b1 = which ? lf_b1 : cg_b1;
    const float* w2 = which ? lf_w2 : cg_w2;
    const float* b2 = which ? lf_b2 : cg_b2;
    __syncthreads();

    const f32x4* wv = (const f32x4*)(w1 + (size_t)t * 512);
    const f32x4* fv = (const f32x4*)fus;
    float s = 0.0f;
    #pragma unroll 4
    for (int k = 0; k < 128; ++k) {
        f32x4 f = fv[k], w = wv[k];
        s = fmaf(f.x, w.x, fmaf(f.y, w.y, fmaf(f.z, w.z, fmaf(f.w, w.w, s))));
    }
    hid[t] = fmaxf(s + b1[t], 0.0f);
    __syncthreads();

    const f32x4* w2v = (const f32x4*)(w2 + (size_t)t * 256);
    const f32x4* hv = (const f32x4*)hid;
    float s2 = 0.0f;
    #pragma unroll 4
    for (int k = 0; k < 64; ++k) {
        f32x4 h = hv[k], w = w2v[k];
        s2 = fmaf(h.x, w.x, fmaf(h.y, w.y, fmaf(h.z, w.z, fmaf(h.w, w.w, s2))));
    }
    s2 += b2[t];
    if (which == 0) {
        ws_cg[b * 256 + t] = 1.0f + 0.5f / (1.0f + expf(-s2));   // pre-biased gate
    } else {
        out_gl[b * 256 + t] = fus[256 + t] + 0.4f * tanhf(s2);
    }
}

// ---------------------------------------------------------------------------
// K3: guided_feat = feat * (1 + 0.6*rm) * gate[c]. 4 rows/block, nt stores.
// ---------------------------------------------------------------------------
__global__ __launch_bounds__(256) void kern_guided(
    const float* __restrict__ feat, const float* __restrict__ rm,
    const float* __restrict__ ws_cg, float* __restrict__ out_gf)
{
    const int blk = blockIdx.x;          // b*64 + g
    const int b = blk >> 6;
    const int c0 = (blk & 63) * RPB;
    const float g0 = ws_cg[b * C_ + c0 + 0];
    const float g1 = ws_cg[b * C_ + c0 + 1];
    const float g2 = ws_cg[b * C_ + c0 + 2];
    const float g3 = ws_cg[b * C_ + c0 + 3];

    const size_t row0 = ((size_t)b * C_ + c0) * HW;
    const f32x4* fr = (const f32x4*)(feat + row0);
    f32x4* orow = (f32x4*)(out_gf + row0);
    const f32x4* r4 = (const f32x4*)(rm + (size_t)b * HW);

    #pragma unroll 2
    for (int i = threadIdx.x; i < HW4; i += 256) {
        f32x4 r = r4[i];
        f32x4 m;
        m.x = 1.0f + 0.6f * r.x;
        m.y = 1.0f + 0.6f * r.y;
        m.z = 1.0f + 0.6f * r.z;
        m.w = 1.0f + 0.6f * r.w;
        f32x4 f0 = fr[i];
        f32x4 f1 = fr[i + HW4];
        f32x4 f2 = fr[i + 2 * HW4];
        f32x4 f3 = fr[i + 3 * HW4];
        f32x4 o0, o1, o2, o3;
        o0.x = f0.x * m.x * g0; o0.y = f0.y * m.y * g0;
        o0.z = f0.z * m.z * g0; o0.w = f0.w * m.w * g0;
        o1.x = f1.x * m.x * g1; o1.y = f1.y * m.y * g1;
        o1.z = f1.z * m.z * g1; o1.w = f1.w * m.w * g1;
        o2.x = f2.x * m.x * g2; o2.y = f2.y * m.y * g2;
        o2.z = f2.z * m.z * g2; o2.w = f2.w * m.w * g2;
        o3.x = f3.x * m.x * g3; o3.y = f3.y * m.y * g3;
        o3.z = f3.z * m.z * g3; o3.w = f3.w * m.w * g3;
        __builtin_nontemporal_store(o0, &orow[i]);
        __builtin_nontemporal_store(o1, &orow[i + HW4]);
        __builtin_nontemporal_store(o2, &orow[i + 2 * HW4]);
        __builtin_nontemporal_store(o3, &orow[i + 3 * HW4]);
    }
}

extern "C" void kernel_launch(void* const* d_in, const int* in_sizes, int n_in,
                              void* d_out, int out_size, void* d_ws, size_t ws_size,
                              hipStream_t stream) {
    const float* feat     = (const float*)d_in[0];
    const float* lang     = (const float*)d_in[1];
    const float* xywh     = (const float*)d_in[2];
    const float* conv1_w  = (const float*)d_in[3];
    const float* conv1_b  = (const float*)d_in[4];
    const float* conv2_w  = (const float*)d_in[5];
    const float* conv2_b  = (const float*)d_in[6];
    const float* cg_w1    = (const float*)d_in[7];
    const float* cg_b1    = (const float*)d_in[8];
    const float* cg_w2    = (const float*)d_in[9];
    const float* cg_b2    = (const float*)d_in[10];
    const float* lf_w1    = (const float*)d_in[11];
    const float* lf_b1    = (const float*)d_in[12];
    const float* lf_w2    = (const float*)d_in[13];
    const float* lf_b2    = (const float*)d_in[14];

    float* out = (float*)d_out;
    const size_t N_GF = (size_t)B_ * C_ * HW;    // 33554432
    float* out_gf    = out;
    float* out_gl    = out_gf + N_GF;            // 8192
    float* out_boxes = out_gl + (size_t)B_ * C_; // 128
    float* out_rm    = out_boxes + B_ * 4;       // 131072
    float* out_pf    = out_rm + (size_t)B_ * HW; // 8192

    float* wsf   = (float*)d_ws;
    float* ws_cg = wsf;                    // 8192 pre-biased gates

    (void)ws_size; (void)in_sizes; (void)n_in; (void)out_size;

    kern_pf<<<B_ * C_ / RPB, 256, 0, stream>>>(feat, xywh,
                                               conv1_w, conv1_b, conv2_w, conv2_b,
                                               out_boxes, out_rm, out_pf);
    kern_mlp<<<B_ * 2, 256, 0, stream>>>(out_pf, lang,
                                         cg_w1, cg_b1, cg_w2, cg_b2,
                                         lf_w1, lf_b1, lf_w2, lf_b2,
                                         ws_cg, out_gl);
    kern_guided<<<B_ * C_ / RPB, 256, 0, stream>>>(feat, out_rm, ws_cg, out_gf);
}

// Round 8
// 94.293 us; speedup vs baseline: 1.0085x; 1.0085x over previous
//
#include <hip/hip_runtime.h>
#include <hip/hip_cooperative_groups.h>
#include <math.h>

#define B_  32
#define C_  256
#define H_  64
#define W_  64
#define HW  (H_*W_)          // 4096
#define HW4 (HW/4)           // 1024
#define MRPB 8               // mega: 8 rows/block -> grid 1024 (4 blocks/CU co-resident)
#define RPB 4                // fallback streaming kernels

namespace cg = cooperative_groups;

typedef float f32x4 __attribute__((ext_vector_type(4)));

__device__ __forceinline__ float clamp01(float v) {
    return fminf(fmaxf(v, 0.0f), 1.0f);
}

// ---------------------------------------------------------------------------
// Shared device helpers (box math + separable rm table), used by both paths.
// ---------------------------------------------------------------------------
struct BoxParams {
    float bx1, by1, bx2, by2, mx1, my1, mx2, my2;
};

__device__ __forceinline__ BoxParams box_math(const float* __restrict__ xywh, int b) {
    const float xc = xywh[b * 4 + 0];
    const float yc = xywh[b * 4 + 1];
    const float bw = xywh[b * 4 + 2];
    const float bh = xywh[b * 4 + 3];

    float x1 = clamp01(xc - bw * 0.5f);
    float y1 = clamp01(yc - bh * 0.5f);
    float x2 = clamp01(xc + bw * 0.5f);
    float y2 = clamp01(yc + bh * 0.5f);
    float xl = fminf(x1, x2), xh = fmaxf(x1, x2);
    float yl = fminf(y1, y2), yh = fmaxf(y1, y2);
    float w_ = fmaxf(xh - xl, 1e-6f);
    float h_ = fmaxf(yh - yl, 1e-6f);
    float cx = (xh + xl) * 0.5f, cy = (yh + yl) * 0.5f;
    BoxParams p;
    p.bx1 = clamp01(cx - w_ * 0.5f);
    p.by1 = clamp01(cy - h_ * 0.5f);
    p.bx2 = clamp01(cx + w_ * 0.5f);
    p.by2 = clamp01(cy + h_ * 0.5f);
    float ww = fmaxf(p.bx2 - p.bx1, 1e-4f);
    float hh = fmaxf(p.by2 - p.by1, 1e-4f);
    float diag = sqrtf(ww * ww + hh * hh);
    float margin = fminf(fmaxf(diag * 0.2f, 0.02f), 0.2f);
    p.mx1 = clamp01(p.bx1 - margin);
    p.my1 = clamp01(p.by1 - margin);
    p.mx2 = clamp01(p.bx2 + margin);
    p.my2 = clamp01(p.by2 + margin);
    return p;
}

// builds xpat/ypat/tbl in LDS. Requires sw1/sb1/sw2 loaded + __syncthreads done.
__device__ __forceinline__ void build_tables(
    int t, const BoxParams& p, float b2v,
    const float* sw1, const float* sb1, const float* sw2,
    int* xpat, int* ypat, float* tbl)
{
    if (t < 64) {
        const int x = t;
        int pp = 0;
        #pragma unroll
        for (int k = 0; k < 3; ++k) {
            const int xx = x + k - 1;
            float gx = (float)((double)xx / 63.0);
            bool in = (xx >= 0) && (xx < W_) && (gx >= p.mx1) && (gx <= p.mx2);
            pp |= (in ? 1 : 0) << k;
        }
        xpat[x] = pp;
    } else if (t < 128) {
        const int y = t - 64;
        int pp = 0;
        #pragma unroll
        for (int k = 0; k < 3; ++k) {
            const int yy = y + k - 1;
            float gy = (float)((double)yy / 63.0);
            bool in = (yy >= 0) && (yy < H_) && (gy >= p.my1) && (gy <= p.my2);
            pp |= (in ? 1 : 0) << k;
        }
        ypat[y] = pp;
    } else if (t < 192) {
        const int e = t - 128;           // e = yp*8 + xp
        const int xp = e & 7, yp = e >> 3;
        float mv[9];
        #pragma unroll
        for (int ky = 0; ky < 3; ++ky)
            #pragma unroll
            for (int kx = 0; kx < 3; ++kx)
                mv[ky * 3 + kx] = (((yp >> ky) & 1) && ((xp >> kx) & 1)) ? 1.0f : 0.0f;
        float z = b2v;
        #pragma unroll
        for (int oc = 0; oc < 16; ++oc) {
            float hsum = sb1[oc];
            #pragma unroll
            for (int k = 0; k < 9; ++k) hsum = fmaf(mv[k], sw1[oc * 9 + k], hsum);
            z = fmaf(fmaxf(hsum, 0.0f), sw2[oc], z);
        }
        tbl[e] = 1.0f / (1.0f + expf(-z));
    }
}

// ===========================================================================
// Mega-kernel (cooperative, grid=1024, block=256, needs 4 blocks/CU):
// ===========================================================================
__global__ __launch_bounds__(256, 4) void kern_mega(
    const float* __restrict__ feat, const float* __restrict__ lang,
    const float* __restrict__ xywh,
    const float* __restrict__ conv1_w, const float* __restrict__ conv1_b,
    const float* __restrict__ conv2_w, const float* __restrict__ conv2_b,
    const float* __restrict__ cg_w1, const float* __restrict__ cg_b1,
    const float* __restrict__ cg_w2, const float* __restrict__ cg_b2,
    const float* __restrict__ lf_w1, const float* __restrict__ lf_b1,
    const float* __restrict__ lf_w2, const float* __restrict__ lf_b2,
    float* __restrict__ out_gf, float* __restrict__ out_gl,
    float* __restrict__ out_boxes, float* __restrict__ out_rm,
    float* __restrict__ out_pf, float* __restrict__ ws_cg)
{
    cg::grid_group grid = cg::this_grid();

    const int blk = blockIdx.x;          // b*32 + g
    const int b = blk >> 5;
    const int g = blk & 31;
    const int c0 = g * MRPB;
    const int t = threadIdx.x;

    __shared__ f32x4 rm4_lds[HW4];       // 16 KB, persists across grid syncs
    __shared__ __align__(16) char scratch[3072];

    float* sw1   = (float*)(scratch);          // 144 @ 0
    float* sb1   = (float*)(scratch + 576);    // 16
    float* sw2   = (float*)(scratch + 640);    // 16
    float* tbl   = (float*)(scratch + 704);    // 64
    int*   xpat  = (int*)  (scratch + 960);    // 64
    int*   ypat  = (int*)  (scratch + 1216);   // 64
    float* sreda = (float*)(scratch + 1472);   // 4
    float* sredp = (float*)(scratch + 1536);   // 4*MRPB = 32 floats
    // phase-2 views (phase-0/1 tables dead by then)
    float* fus   = (float*)(scratch);          // 512 @ 0
    float* hid   = (float*)(scratch + 2048);   // 256

    float* rm_lds = (float*)rm4_lds;

    if (t < 144)                 sw1[t]       = conv1_w[t];
    else if (t < 160)            sb1[t - 144] = conv1_b[t - 144];
    else if (t < 176)            sw2[t - 160] = conv2_w[t - 160];
    const float b2v = conv2_b[0];

    const BoxParams bp = box_math(xywh, b);
    if (t == 0 && g == 0) {
        out_boxes[b * 4 + 0] = bp.bx1;
        out_boxes[b * 4 + 1] = bp.by1;
        out_boxes[b * 4 + 2] = bp.bx2;
        out_boxes[b * 4 + 3] = bp.by2;
    }
    __syncthreads();   // weights visible

    build_tables(t, bp, b2v, sw1, sb1, sw2, xpat, ypat, tbl);
    __syncthreads();

    // rm row -> LDS + area partials
    float asum = 0.0f;
    for (int p = t; p < HW; p += 256) {
        const int y = p >> 6;
        const int x = p & 63;
        float rm = tbl[ypat[y] * 8 + xpat[x]];
        rm_lds[p] = rm;
        asum += rm;
    }
    #pragma unroll
    for (int off = 32; off > 0; off >>= 1) asum += __shfl_down(asum, off, 64);
    const int lane = t & 63, wid = t >> 6;
    if (lane == 0) sreda[wid] = asum;
    __syncthreads();
    const float inv = 1.0f / fmaxf(sreda[0] + sreda[1] + sreda[2] + sreda[3], 1.0f);

    if (g == 0) {
        f32x4* orm = (f32x4*)(out_rm + (size_t)b * HW);
        for (int i = t; i < HW4; i += 256) orm[i] = rm4_lds[i];
    }

    // ---- phase 1: pf dot over 8 rows ----
    const size_t row0 = ((size_t)b * C_ + c0) * HW;
    const f32x4* fr = (const f32x4*)(feat + row0);
    {
        float s[MRPB];
        #pragma unroll
        for (int j = 0; j < MRPB; ++j) s[j] = 0.0f;
        for (int i = t; i < HW4; i += 256) {
            f32x4 r = rm4_lds[i];
            #pragma unroll
            for (int j = 0; j < MRPB; ++j) {
                f32x4 f = fr[i + j * HW4];
                s[j] = fmaf(f.x, r.x, fmaf(f.y, r.y, fmaf(f.z, r.z, fmaf(f.w, r.w, s[j]))));
            }
        }
        #pragma unroll
        for (int j = 0; j < MRPB; ++j) {
            #pragma unroll
            for (int off = 32; off > 0; off >>= 1) s[j] += __shfl_down(s[j], off, 64);
        }
        if (lane == 0) {
            #pragma unroll
            for (int j = 0; j < MRPB; ++j) sredp[wid * MRPB + j] = s[j];
        }
        __syncthreads();
        if (t < MRPB) {
            float tot = sredp[0 * MRPB + t] + sredp[1 * MRPB + t] +
                        sredp[2 * MRPB + t] + sredp[3 * MRPB + t];
            out_pf[b * C_ + c0 + t] = tot * inv;
        }
    }

    grid.sync();

    // ---- phase 2: MLPs on blocks 0..63 ----
    if (blk < 64) {
        const int bb = blk >> 1;
        const int which = blk & 1;

        fus[t]       = out_pf[bb * 256 + t];
        fus[256 + t] = lang[bb * 256 + t];

        const float* w1 = which ? lf_w1 : cg_w1;
        const float* b1 = which ? lf_b1 : cg_b1;
        const float* w2 = which ? lf_w2 : cg_w2;
        const float* b2 = which ? lf_b2 : cg_b2;
        __syncthreads();

        const f32x4* wv = (const f32x4*)(w1 + (size_t)t * 512);
        const f32x4* fv = (const f32x4*)fus;
        float s = 0.0f;
        #pragma unroll 4
        for (int k = 0; k < 128; ++k) {
            f32x4 f = fv[k], w = wv[k];
            s = fmaf(f.x, w.x, fmaf(f.y, w.y, fmaf(f.z, w.z, fmaf(f.w, w.w, s))));
        }
        hid[t] = fmaxf(s + b1[t], 0.0f);
        __syncthreads();

        const f32x4* w2v = (const f32x4*)(w2 + (size_t)t * 256);
        const f32x4* hv = (const f32x4*)hid;
        float s2 = 0.0f;
        #pragma unroll 4
        for (int k = 0; k < 64; ++k) {
            f32x4 h = hv[k], w = w2v[k];
            s2 = fmaf(h.x, w.x, fmaf(h.y, w.y, fmaf(h.z, w.z, fmaf(h.w, w.w, s2))));
        }
        s2 += b2[t];
        if (which == 0) {
            ws_cg[bb * 256 + t] = 1.0f + 0.5f / (1.0f + expf(-s2));
        } else {
            out_gl[bb * 256 + t] = fus[256 + t] + 0.4f * tanhf(s2);
        }
    }

    grid.sync();

    // ---- phase 3: guided stream (rm still in LDS) ----
    float gr[MRPB];
    #pragma unroll
    for (int j = 0; j < MRPB; ++j) gr[j] = ws_cg[b * C_ + c0 + j];

    f32x4* orow = (f32x4*)(out_gf + row0);
    for (int i = t; i < HW4; i += 256) {
        f32x4 r = rm4_lds[i];
        f32x4 m;
        m.x = 1.0f + 0.6f * r.x;
        m.y = 1.0f + 0.6f * r.y;
        m.z = 1.0f + 0.6f * r.z;
        m.w = 1.0f + 0.6f * r.w;
        #pragma unroll
        for (int j = 0; j < MRPB; ++j) {
            f32x4 f = fr[i + j * HW4];
            f32x4 o;
            o.x = f.x * m.x * gr[j];
            o.y = f.y * m.y * gr[j];
            o.z = f.z * m.z * gr[j];
            o.w = f.w * m.w * gr[j];
            __builtin_nontemporal_store(o, &orow[i + j * HW4]);
        }
    }
}

// ===========================================================================
// Fallback path (R6 kernels, known-pass @ 95 µs)
// ===========================================================================
__global__ __launch_bounds__(256) void kern_pf(
    const float* __restrict__ feat, const float* __restrict__ xywh,
    const float* __restrict__ conv1_w, const float* __restrict__ conv1_b,
    const float* __restrict__ conv2_w, const float* __restrict__ conv2_b,
    float* __restrict__ out_boxes, float* __restrict__ out_rm,
    float* __restrict__ out_pf)
{
    const int blk = blockIdx.x;          // b*64 + g
    const int b = blk >> 6;
    const int g = blk & 63;
    const int c0 = g * RPB;
    const int t = threadIdx.x;

    __shared__ float sw1[16 * 9];
    __shared__ float sb1[16];
    __shared__ float sw2[16];
    __shared__ float tbl[64];
    __shared__ int   xpat[64];
    __shared__ int   ypat[64];
    __shared__ f32x4 rm4_lds[HW4];
    __shared__ float sreda[4];
    __shared__ f32x4 sredv[4];

    float* rm_lds = (float*)rm4_lds;

    if (t < 144)                 sw1[t]       = conv1_w[t];
    else if (t < 160)            sb1[t - 144] = conv1_b[t - 144];
    else if (t < 176)            sw2[t - 160] = conv2_w[t - 160];
    const float b2v = conv2_b[0];

    const BoxParams bp = box_math(xywh, b);
    if (t == 0 && g == 0) {
        out_boxes[b * 4 + 0] = bp.bx1;
        out_boxes[b * 4 + 1] = bp.by1;
        out_boxes[b * 4 + 2] = bp.bx2;
        out_boxes[b * 4 + 3] = bp.by2;
    }
    __syncthreads();

    build_tables(t, bp, b2v, sw1, sb1, sw2, xpat, ypat, tbl);
    __syncthreads();

    float asum = 0.0f;
    for (int p = t; p < HW; p += 256) {
        const int y = p >> 6;
        const int x = p & 63;
        float rm = tbl[ypat[y] * 8 + xpat[x]];
        rm_lds[p] = rm;
        asum += rm;
    }
    #pragma unroll
    for (int off = 32; off > 0; off >>= 1) asum += __shfl_down(asum, off, 64);
    const int lane = t & 63, wid = t >> 6;
    if (lane == 0) sreda[wid] = asum;
    __syncthreads();
    const float inv = 1.0f / fmaxf(sreda[0] + sreda[1] + sreda[2] + sreda[3], 1.0f);

    if (g == 0) {
        f32x4* orm = (f32x4*)(out_rm + (size_t)b * HW);
        for (int i = t; i < HW4; i += 256) orm[i] = rm4_lds[i];
    }

    const f32x4* fr = (const f32x4*)(feat + ((size_t)b * C_ + c0) * HW);
    float s0 = 0.f, s1 = 0.f, s2 = 0.f, s3 = 0.f;
    #pragma unroll 2
    for (int i = t; i < HW4; i += 256) {
        f32x4 r = rm4_lds[i];
        f32x4 f0 = fr[i];
        f32x4 f1 = fr[i + HW4];
        f32x4 f2 = fr[i + 2 * HW4];
        f32x4 f3 = fr[i + 3 * HW4];
        s0 = fmaf(f0.x, r.x, fmaf(f0.y, r.y, fmaf(f0.z, r.z, fmaf(f0.w, r.w, s0))));
        s1 = fmaf(f1.x, r.x, fmaf(f1.y, r.y, fmaf(f1.z, r.z, fmaf(f1.w, r.w, s1))));
        s2 = fmaf(f2.x, r.x, fmaf(f2.y, r.y, fmaf(f2.z, r.z, fmaf(f2.w, r.w, s2))));
        s3 = fmaf(f3.x, r.x, fmaf(f3.y, r.y, fmaf(f3.z, r.z, fmaf(f3.w, r.w, s3))));
    }
    #pragma unroll
    for (int off = 32; off > 0; off >>= 1) {
        s0 += __shfl_down(s0, off, 64);
        s1 += __shfl_down(s1, off, 64);
        s2 += __shfl_down(s2, off, 64);
        s3 += __shfl_down(s3, off, 64);
    }
    if (lane == 0) { f32x4 v; v.x = s0; v.y = s1; v.z = s2; v.w = s3; sredv[wid] = v; }
    __syncthreads();
    if (t == 0) {
        f32x4 t0 = sredv[0], t1 = sredv[1], t2 = sredv[2], t3 = sredv[3];
        out_pf[b * C_ + c0 + 0] = (t0.x + t1.x + t2.x + t3.x) * inv;
        out_pf[b * C_ + c0 + 1] = (t0.y + t1.y + t2.y + t3.y) * inv;
        out_pf[b * C_ + c0 + 2] = (t0.z + t1.z + t2.z + t3.z) * inv;
        out_pf[b * C_ + c0 + 3] = (t0.w + t1.w + t2.w + t3.w) * inv;
    }
}

__global__ __launch_bounds__(256) void kern_mlp(
    const float* __restrict__ pf, const float* __restrict__ lang,
    const float* __restrict__ cg_w1, const float* __restrict__ cg_b1,
    const float* __restrict__ cg_w2, const float* __restrict__ cg_b2,
    const float* __restrict__ lf_w1, const float* __restrict__ lf_b1,
    const float* __restrict__ lf_w2, const float* __restrict__ lf_b2,
    float* __restrict__ ws_cg, float* __restrict__ out_gl)
{
    const int b = blockIdx.x >> 1;
    const int which = blockIdx.x & 1;
    const int t = threadIdx.x;
    __shared__ float fus[512];
    __shared__ float hid[256];

    fus[t]       = pf[b * 256 + t];
    fus[256 + t] = lang[b * 256 + t];

    const float* w1 = which ? lf_w1 : cg_w1;
    const float* b1 = which ? lf_b1 : cg_b1;
    const float* w2 = which ? lf_w2 : cg_w2;
    const float* b2 = which ? lf_b2 : cg_b2;
    __syncthreads();

    const f32x4* wv = (const f32x4*)(w1 + (size_t)t * 512);
    const f32x4* fv = (const f32x4*)fus;
    float s = 0.0f;
    #pragma unroll 4
    for (int k = 0; k < 128; ++k) {
        f32x4 f = fv[k], w = wv[k];
        s = fmaf(f.x, w.x, fmaf(f.y, w.y, fmaf(f.z, w.z, fmaf(f.w, w.w, s))));
    }
    hid[t] = fmaxf(s + b1[t], 0.0f);
    __syncthreads();

    const f32x4* w2v = (const f32x4*)(w2 + (size_t)t * 256);
    const f32x4* hv = (const f32x4*)hid;
    float s2 = 0.0f;
    #pragma unroll 4
    for (int k = 0; k < 64; ++k) {
        f32x4 h = hv[k], w = w2v[k];
        s2 = fmaf(h.x, w.x, fmaf(h.y, w.y, fmaf(h.z, w.z, fmaf(h.w, w.w, s2))));
    }
    s2 += b2[t];
    if (which == 0) {
        ws_cg[b * 256 + t] = 1.0f + 0.5f / (1.0f + expf(-s2));
    } else {
        out_gl[b * 256 + t] = fus[256 + t] + 0.4f * tanhf(s2);
    }
}

__global__ __launch_bounds__(256) void kern_guided(
    const float* __restrict__ feat, const float* __restrict__ rm,
    const float* __restrict__ ws_cg, float* __restrict__ out_gf)
{
    const int blk = blockIdx.x;          // b*64 + g
    const int b = blk >> 6;
    const int c0 = (blk & 63) * RPB;
    const float g0 = ws_cg[b * C_ + c0 + 0];
    const float g1 = ws_cg[b * C_ + c0 + 1];
    const float g2 = ws_cg[b * C_ + c0 + 2];
    const float g3 = ws_cg[b * C_ + c0 + 3];

    const size_t row0 = ((size_t)b * C_ + c0) * HW;
    const f32x4* fr = (const f32x4*)(feat + row0);
    f32x4* orow = (f32x4*)(out_gf + row0);
    const f32x4* r4 = (const f32x4*)(rm + (size_t)b * HW);

    #pragma unroll 2
    for (int i = threadIdx.x; i < HW4; i += 256) {
        f32x4 r = r4[i];
        f32x4 m;
        m.x = 1.0f + 0.6f * r.x;
        m.y = 1.0f + 0.6f * r.y;
        m.z = 1.0f + 0.6f * r.z;
        m.w = 1.0f + 0.6f * r.w;
        f32x4 f0 = fr[i];
        f32x4 f1 = fr[i + HW4];
        f32x4 f2 = fr[i + 2 * HW4];
        f32x4 f3 = fr[i + 3 * HW4];
        f32x4 o0, o1, o2, o3;
        o0.x = f0.x * m.x * g0; o0.y = f0.y * m.y * g0;
        o0.z = f0.z * m.z * g0; o0.w = f0.w * m.w * g0;
        o1.x = f1.x * m.x * g1; o1.y = f1.y * m.y * g1;
        o1.z = f1.z * m.z * g1; o1.w = f1.w * m.w * g1;
        o2.x = f2.x * m.x * g2; o2.y = f2.y * m.y * g2;
        o2.z = f2.z * m.z * g2; o2.w = f2.w * m.w * g2;
        o3.x = f3.x * m.x * g3; o3.y = f3.y * m.y * g3;
        o3.z = f3.z * m.z * g3; o3.w = f3.w * m.w * g3;
        __builtin_nontemporal_store(o0, &orow[i]);
        __builtin_nontemporal_store(o1, &orow[i + HW4]);
        __builtin_nontemporal_store(o2, &orow[i + 2 * HW4]);
        __builtin_nontemporal_store(o3, &orow[i + 3 * HW4]);
    }
}

extern "C" void kernel_launch(void* const* d_in, const int* in_sizes, int n_in,
                              void* d_out, int out_size, void* d_ws, size_t ws_size,
                              hipStream_t stream) {
    const float* feat     = (const float*)d_in[0];
    const float* lang     = (const float*)d_in[1];
    const float* xywh     = (const float*)d_in[2];
    const float* conv1_w  = (const float*)d_in[3];
    const float* conv1_b  = (const float*)d_in[4];
    const float* conv2_w  = (const float*)d_in[5];
    const float* conv2_b  = (const float*)d_in[6];
    const float* cg_w1    = (const float*)d_in[7];
    const float* cg_b1    = (const float*)d_in[8];
    const float* cg_w2    = (const float*)d_in[9];
    const float* cg_b2    = (const float*)d_in[10];
    const float* lf_w1    = (const float*)d_in[11];
    const float* lf_b1    = (const float*)d_in[12];
    const float* lf_w2    = (const float*)d_in[13];
    const float* lf_b2    = (const float*)d_in[14];

    float* out = (float*)d_out;
    const size_t N_GF = (size_t)B_ * C_ * HW;    // 33554432
    float* out_gf    = out;
    float* out_gl    = out_gf + N_GF;            // 8192
    float* out_boxes = out_gl + (size_t)B_ * C_; // 128
    float* out_rm    = out_boxes + B_ * 4;       // 131072
    float* out_pf    = out_rm + (size_t)B_ * HW; // 8192

    float* ws_cg = (float*)d_ws;                 // 8192 pre-biased gates

    (void)ws_size; (void)in_sizes; (void)n_in; (void)out_size;

    const int MEGA_GRID = B_ * C_ / MRPB;        // 1024
    int nb = 0;
    hipError_t oe = hipOccupancyMaxActiveBlocksPerMultiprocessor(&nb, kern_mega, 256, 0);
    const bool coop_ok = (oe == hipSuccess) && (nb * 256 >= MEGA_GRID);  // 256 CUs

    if (coop_ok) {
        void* args[] = {
            (void*)&feat, (void*)&lang, (void*)&xywh,
            (void*)&conv1_w, (void*)&conv1_b, (void*)&conv2_w, (void*)&conv2_b,
            (void*)&cg_w1, (void*)&cg_b1, (void*)&cg_w2, (void*)&cg_b2,
            (void*)&lf_w1, (void*)&lf_b1, (void*)&lf_w2, (void*)&lf_b2,
            (void*)&out_gf, (void*)&out_gl, (void*)&out_boxes, (void*)&out_rm,
            (void*)&out_pf, (void*)&ws_cg
        };
        hipLaunchCooperativeKernel((const void*)kern_mega,
                                   dim3(MEGA_GRID), dim3(256),
                                   args, 0, stream);
    } else {
        kern_pf<<<B_ * C_ / RPB, 256, 0, stream>>>(feat, xywh,
                                                   conv1_w, conv1_b, conv2_w, conv2_b,
                                                   out_boxes, out_rm, out_pf);
        kern_mlp<<<B_ * 2, 256, 0, stream>>>(out_pf, lang,
                                             cg_w1, cg_b1, cg_w2, cg_b2,
                                             lf_w1, lf_b1, lf_w2, lf_b2,
                                             ws_cg, out_gl);
        kern_guided<<<B_ * C_ / RPB, 256, 0, stream>>>(feat, out_rm, ws_cg, out_gf);
    }
}